// Round 3
// baseline (308.327 us; speedup 1.0000x reference)
//
#include <hip/hip_runtime.h>
#include <stdint.h>

// Problem constants (fixed by reference)
#define TP_      8
#define M_DIM    4096
#define K_DIM    8192
#define N_DIM    1024      // N_LOCAL
#define KL_      1024      // K_LOCAL
#define BM       256
#define BN       256
#define SPLITK   4
#define KSLICE   (K_DIM / SPLITK)   // 2048
#define MN4      (M_DIM * N_DIM / 4)
#define KCHUNKS  (K_DIM / 32)       // 256 k32-chunks per 16-row/col group

typedef _Float16 f16;
typedef f16 f16x8 __attribute__((ext_vector_type(8)));
typedef float f32x4 __attribute__((ext_vector_type(4)));

// 8x fp32 -> fp16 (v_cvt_f16_f32, RN)
__device__ __forceinline__ f16x8 cvt8(float4 a, float4 b) {
    f16x8 r;
    r[0] = (f16)a.x; r[1] = (f16)a.y; r[2] = (f16)a.z; r[3] = (f16)a.w;
    r[4] = (f16)b.x; r[5] = (f16)b.y; r[6] = (f16)b.z; r[7] = (f16)b.w;
    return r;
}

// async global->LDS, 16B/lane; dest = wave-uniform base + lane*16 (m104/m108)
__device__ __forceinline__ void lds_load16(const void* g, void* l) {
    __builtin_amdgcn_global_load_lds(
        (const __attribute__((address_space(1))) void*)g,
        (__attribute__((address_space(3))) void*)l, 16, 0, 0);
}

// Fragment-major layout (both operands): chunk c = group*KCHUNKS + k32;
// chunk holds 512 halfs; slot lane*8 = X[group*16 + (lane&15)][k32*32 + (lane>>4)*8 ..+8].
// A wave touching one chunk reads/writes base + lane*16B: ONE 1KB transaction.

// ---------- kernel 1: convert + repack W -> fragment-major fp16 (verified) ----------
__global__ __launch_bounds__(256) void conv_w_kernel(
        const float* __restrict__ W, f16* __restrict__ Bfrag) {
    __shared__ float tile[64][68];                 // [k][n], pad 68
    const int t  = threadIdx.x;
    const int n0 = blockIdx.x * 64;
    const int k0 = blockIdx.y * 64;
    #pragma unroll
    for (int l = 0; l < 4; l++) {
        int kr = l * 16 + (t >> 4);
        float4 v = *(const float4*)&W[(size_t)(k0 + kr) * N_DIM + n0 + (t & 15) * 4];
        *(float4*)&tile[kr][(t & 15) * 4] = v;
    }
    __syncthreads();
    const int jtl   = t >> 6;
    const int kt32l = (t >> 5) & 1;
    const int u     = t & 31;
    const int rr    = u & 15;
    const int qp    = u >> 4;
    f16x8 h0, h1;
    #pragma unroll
    for (int kk = 0; kk < 8; kk++)
        h0[kk] = (f16)tile[kt32l * 32 + qp * 16 + kk][jtl * 16 + rr];
    #pragma unroll
    for (int kk = 0; kk < 8; kk++)
        h1[kk] = (f16)tile[kt32l * 32 + qp * 16 + 8 + kk][jtl * 16 + rr];
    size_t chunk = (size_t)(n0 / 16 + jtl) * KCHUNKS + (k0 / 32 + kt32l);
    f16* dst = Bfrag + chunk * 512;
    *(f16x8*)(dst + ((2 * qp)     * 16 + rr) * 8) = h0;
    *(f16x8*)(dst + ((2 * qp + 1) * 16 + rr) * 8) = h1;
}

// ---------- kernel 2: fused gather-A + convert + deep-pipelined GEMM ----------
// 256x256 tile, 8 waves (2M x 4N), BK=64 (2 k32), double-buffered 2x64KB LDS.
// A path: fp32 reg-load from act (coalesced 64B/thread) -> in-reg cvt ->
// ds_write_b128 into frag-major slots (round-1-verified mapping; 8 lanes per
// bank-quad = minimum phases). B path: gload_lds from frag-major Bfrag.
// Cross-wave load visibility: every guard is a counted vmcnt BEFORE a barrier.
//   VMEND ph3: vmcnt(2)  -> B(t+1)k0 landed  (leaves B(t+1)k1 in flight)
//   VMMID ph1: vmcnt(10) -> B(t)k1 landed    (leaves aa(t+1):8 + B(t+1)k0:2)
//   A regs: compiler-counted auto vmcnt at cvt use; A LDS visibility via
//   lgkm drain before ph2's second barrier (DS in-order per wave).
__global__ __launch_bounds__(512, 2) void gemm_fused_kernel(
        const float* __restrict__ act,        // (TP, M, KL) fp32
        const f16* __restrict__ Bfrag,
        float* __restrict__ part) {           // (SPLITK, M, N) fp32
    __shared__ f16 sm[2][64 * 512];           // A chunks 0..31 (mg*2+k2), B 32..63

    const int tid  = threadIdx.x;
    const int w    = tid >> 6;                // wave 0..7
    const int lane = tid & 63;
    const int q    = lane >> 4;
    const int rr   = lane & 15;
    const int wr   = w >> 2;                  // 0..1 (M)
    const int wc   = w & 3;                   // 0..3 (N)
    const int rt   = tid >> 1;                // A-staging row within tile 0..255
    const int hh   = tid & 1;                 // k-half (16 floats) within k32

    // XCD decode: xcd = (z<<1)|(mb&1). Per XCD: one z, 8 unique mb panels
    // (A slice L2-amortized x4 by nb sharing), all 4 nb.
    const int id   = blockIdx.x;              // 0..255
    const int xcd  = id & 7;
    const int slot = id >> 3;                 // 0..31
    const int z    = xcd >> 1;                // 0..3
    const int mb   = (slot >> 2) * 2 + (xcd & 1); // 0..15
    const int nb   = slot & 3;                // 0..3
    const int row0 = mb * BM;
    const int col0 = nb * BN;
    const int kb   = z * KSLICE;              // base k (float index)
    const int kb32 = kb >> 5;
    const int ng0  = col0 >> 4;

    const size_t aRow = (size_t)(row0 + rt) * KL_ + hh * 16;

    f32x4 acc[8][4];
    #pragma unroll
    for (int m = 0; m < 8; m++)
        #pragma unroll
        for (int n = 0; n < 4; n++)
            acc[m][n] = (f32x4){0.f, 0.f, 0.f, 0.f};

    f16x8 af[8];
    f16x8 bf[2];
    float4 aa[8];                             // staged A: 32 fp32 (static idx only)

// A: 8x dwordx4, 64B contiguous per thread per k32 (one shard: k 32-aligned).
#define LOADA(T_) do { \
    _Pragma("unroll") \
    for (int k2_ = 0; k2_ < 2; k2_++) { \
        const int k_ = kb + (T_) * 64 + k2_ * 32; \
        const float* ap_ = act + (size_t)(k_ >> 10) * ((size_t)M_DIM * KL_) \
                           + aRow + (k_ & (KL_ - 1)); \
        _Pragma("unroll") \
        for (int i_ = 0; i_ < 4; i_++) aa[k2_ * 4 + i_] = ((const float4*)ap_)[i_]; \
    } \
} while (0)

// cvt 32 fp32 -> fp16 + 4x ds_write_b128 into frag-major slots (r1-verified).
#define CVTWA(B_) do { \
    _Pragma("unroll") \
    for (int k2_ = 0; k2_ < 2; k2_++) { \
        f16x8 u0_ = cvt8(aa[k2_ * 4 + 0], aa[k2_ * 4 + 1]); \
        f16x8 u1_ = cvt8(aa[k2_ * 4 + 2], aa[k2_ * 4 + 3]); \
        f16* dA_ = &sm[B_][(((rt >> 4) * 2) + k2_) * 512]; \
        *(f16x8*)(dA_ + ((2 * hh)     * 16 + (rt & 15)) * 8) = u0_; \
        *(f16x8*)(dA_ + ((2 * hh + 1) * 16 + (rt & 15)) * 8) = u1_; \
    } \
} while (0)

#define STAGE_B(B_, T_, K2_) do { \
    const int kt32_ = kb32 + 2 * (T_) + (K2_); \
    _Pragma("unroll") \
    for (int j_ = 0; j_ < 2; j_++) { \
        const int ng_ = 2 * w + j_; \
        const f16* g_ = Bfrag + ((size_t)(ng0 + ng_) * KCHUNKS + kt32_) * 512 + lane * 8; \
        lds_load16(g_, &sm[B_][(32 + ng_ * 2 + (K2_)) * 512 + lane * 8]); \
    } \
} while (0)

#define READ_A(B_, K2_) do { \
    _Pragma("unroll") \
    for (int mi_ = 0; mi_ < 8; mi_++) \
        af[mi_] = *(const f16x8*)&sm[B_][((wr * 8 + mi_) * 2 + (K2_)) * 512 + lane * 8]; \
} while (0)

#define READ_B(B_, K2_, NH_) do { \
    _Pragma("unroll") \
    for (int ni_ = 0; ni_ < 2; ni_++) \
        bf[ni_] = *(const f16x8*)&sm[B_][(32 + (wc * 4 + (NH_) * 2 + ni_) * 2 + (K2_)) * 512 + lane * 8]; \
} while (0)

#define MFMA16(NH_) do { \
    __builtin_amdgcn_s_setprio(1); \
    _Pragma("unroll") \
    for (int mi_ = 0; mi_ < 8; mi_++) \
        _Pragma("unroll") \
        for (int ni_ = 0; ni_ < 2; ni_++) \
            acc[mi_][(NH_) * 2 + ni_] = __builtin_amdgcn_mfma_f32_16x16x32_f16( \
                af[mi_], bf[ni_], acc[mi_][(NH_) * 2 + ni_], 0, 0, 0); \
    __builtin_amdgcn_s_setprio(0); \
} while (0)

#define BAR() do { \
    asm volatile("" ::: "memory"); \
    __builtin_amdgcn_s_barrier(); \
    asm volatile("" ::: "memory"); \
} while (0)
#define SBAR0() __builtin_amdgcn_sched_barrier(0)
#define VM0()  asm volatile("s_waitcnt vmcnt(0)" ::: "memory")
#define VM2()  asm volatile("s_waitcnt vmcnt(2)" ::: "memory")
#define VM10() asm volatile("s_waitcnt vmcnt(10)" ::: "memory")
#define LGK0() asm volatile("s_waitcnt lgkmcnt(0)" ::: "memory")

// One K-tile = 4 phases; staging tiles prefetch tile T_+1.
#define TILE(P_, T_, STG_, VMMID_, VMEND_) do { \
    if (STG_) LOADA((T_) + 1); \
    READ_A(P_, 0); READ_B(P_, 0, 0); \
    BAR(); SBAR0(); MFMA16(0); BAR(); \
    READ_B(P_, 0, 1); \
    if (STG_) STAGE_B((P_) ^ 1, (T_) + 1, 0); \
    BAR(); SBAR0(); MFMA16(1); VMMID_; BAR(); \
    if (STG_) CVTWA((P_) ^ 1); \
    READ_A(P_, 1); READ_B(P_, 1, 0); \
    BAR(); SBAR0(); MFMA16(0); BAR(); \
    READ_B(P_, 1, 1); \
    if (STG_) STAGE_B((P_) ^ 1, (T_) + 1, 1); \
    BAR(); SBAR0(); MFMA16(1); VMEND_; BAR(); \
} while (0)

    // ---- prologue: tile 0 -> buf0 ----
    LOADA(0);                 // 8 vmem (regs)
    STAGE_B(0, 0, 0);         // 2 gl_lds
    STAGE_B(0, 0, 1);         // 2 gl_lds
    CVTWA(0);                 // compiler auto vmcnt(4) for aa
    VM0();                    // B(0) landed
    LGK0();                   // A ds_writes drained
    __builtin_amdgcn_s_barrier();
    asm volatile("" ::: "memory");

    // ---- main loop: tiles 0..30 stage t+1; tile 31 = tail ----
    #pragma unroll 1
    for (int t = 0; t < 30; t += 2) {
        TILE(0, t,     1, VM10(), VM2());
        TILE(1, t + 1, 1, VM10(), VM2());
    }
    TILE(0, 30, 1, VM10(), VM2());
    TILE(1, 31, 0, VM0(), (void)0);

    // ---- epilogue: C/D layout col = lane&15, row = q*4 + reg (validated) ----
    float* Pz = part + (size_t)z * M_DIM * N_DIM;
    #pragma unroll
    for (int m = 0; m < 8; m++) {
        const int gm = row0 + wr * 128 + m * 16 + q * 4;
        #pragma unroll
        for (int n = 0; n < 4; n++) {
            const int gn = col0 + wc * 64 + n * 16 + rr;
            #pragma unroll
            for (int r2 = 0; r2 < 4; r2++)
                Pz[(size_t)(gm + r2) * N_DIM + gn] = acc[m][n][r2];
        }
    }
#undef LOADA
#undef CVTWA
#undef STAGE_B
#undef READ_A
#undef READ_B
#undef MFMA16
#undef BAR
#undef SBAR0
#undef VM0
#undef VM2
#undef VM10
#undef LGK0
#undef TILE
}

// ---------- kernel 3: reduce 4 partials + bias (verified) ----------
__global__ __launch_bounds__(256) void reduce_kernel(
        const float* __restrict__ part, const float* __restrict__ bias,
        float* __restrict__ out) {
    int p = blockIdx.x * 256 + threadIdx.x;
    const float4* P = (const float4*)part;
    float4 s0 = P[p];
    float4 s1 = P[p + MN4];
    float4 s2 = P[p + 2 * MN4];
    float4 s3 = P[p + 3 * MN4];
    float4 b  = ((const float4*)bias)[p & (N_DIM / 4 - 1)];
    float4 r;
    r.x = s0.x + s1.x + s2.x + s3.x + b.x;
    r.y = s0.y + s1.y + s2.y + s3.y + b.y;
    r.z = s0.z + s1.z + s2.z + s3.z + b.z;
    r.w = s0.w + s1.w + s2.w + s3.w + b.w;
    ((float4*)out)[p] = r;
}

// ---------- fallback (only if ws too small): naive fp32 tiled GEMM ----------
__global__ void gemm_fallback_kernel(const float* __restrict__ act,
                                     const float* __restrict__ W,
                                     const float* __restrict__ bias,
                                     float* __restrict__ out) {
    __shared__ float sA2[32][33];
    __shared__ float sB2[32][33];
    int tx = threadIdx.x, ty = threadIdx.y;
    int m = blockIdx.y * 32 + ty;
    int n = blockIdx.x * 32 + tx;
    float acc = 0.f;
    for (int kt = 0; kt < K_DIM; kt += 32) {
        int ka = kt + tx;
        int r = ka >> 10, kl = ka & (KL_ - 1);
        sA2[ty][tx] = act[((size_t)r * M_DIM + m) * KL_ + kl];
        sB2[ty][tx] = W[(size_t)(kt + ty) * N_DIM + n];
        __syncthreads();
        #pragma unroll
        for (int kk = 0; kk < 32; kk++) acc += sA2[ty][kk] * sB2[kk][tx];
        __syncthreads();
    }
    out[(size_t)m * N_DIM + n] = acc + bias[n];
}

extern "C" void kernel_launch(void* const* d_in, const int* in_sizes, int n_in,
                              void* d_out, int out_size, void* d_ws, size_t ws_size,
                              hipStream_t stream) {
    const float* all_act = (const float*)d_in[0];
    const float* local_W = (const float*)d_in[1];
    const float* bias    = (const float*)d_in[2];
    float* out = (float*)d_out;

    const size_t partBytes = (size_t)SPLITK * M_DIM * N_DIM * sizeof(float);  // 67.1 MB
    const size_t elemsW    = (size_t)K_DIM * N_DIM;                           // 8.4M
    const size_t need = partBytes + elemsW * sizeof(f16);                     // ~83.9 MB

    if (ws_size < need) {
        gemm_fallback_kernel<<<dim3(N_DIM / 32, M_DIM / 32), dim3(32, 32), 0, stream>>>(
            all_act, local_W, bias, out);
        return;
    }

    float* part  = (float*)d_ws;
    f16*   Bfrag = (f16*)((char*)d_ws + partBytes);

    conv_w_kernel<<<dim3(N_DIM / 64, K_DIM / 64), 256, 0, stream>>>(local_W, Bfrag);
    gemm_fused_kernel<<<256, 512, 0, stream>>>(all_act, Bfrag, part);
    reduce_kernel<<<MN4 / 256, 256, 0, stream>>>(part, bias, out);
}

// Round 4
// 294.715 us; speedup vs baseline: 1.0462x; 1.0462x over previous
//
#include <hip/hip_runtime.h>
#include <stdint.h>

// Problem constants (fixed by reference)
#define TP_      8
#define M_DIM    4096
#define K_DIM    8192
#define N_DIM    1024      // N_LOCAL
#define KL_      1024      // K_LOCAL
#define BM       256
#define BN       256
#define SPLITK   4
#define KSLICE   (K_DIM / SPLITK)   // 2048
#define MN4      (M_DIM * N_DIM / 4)
#define KCHUNKS  (K_DIM / 32)       // 256 k32-chunks per 16-row/col group
#define NBLK_A   ((M_DIM / 16) * (K_DIM / 32) / 4)   // 16384 conv-A blocks
#define NBLK_W   ((N_DIM / 64) * (K_DIM / 64))       // 2048  conv-W blocks

typedef _Float16 f16;
typedef f16 f16x8 __attribute__((ext_vector_type(8)));
typedef f16 f16x4 __attribute__((ext_vector_type(4)));
typedef float f32x4 __attribute__((ext_vector_type(4)));

// 8x fp32 -> fp16 (v_cvt_f16_f32, RN)
__device__ __forceinline__ f16x8 cvt8(float4 a, float4 b) {
    f16x8 r;
    r[0] = (f16)a.x; r[1] = (f16)a.y; r[2] = (f16)a.z; r[3] = (f16)a.w;
    r[4] = (f16)b.x; r[5] = (f16)b.y; r[6] = (f16)b.z; r[7] = (f16)b.w;
    return r;
}

// async global->LDS, 16B/lane; dest = wave-uniform base + lane*16 (m104/m108)
__device__ __forceinline__ void lds_load16(const void* g, void* l) {
    __builtin_amdgcn_global_load_lds(
        (const __attribute__((address_space(1))) void*)g,
        (__attribute__((address_space(3))) void*)l, 16, 0, 0);
}

// Fragment-major layout (both operands): chunk c = group*KCHUNKS + k32;
// chunk holds 512 halfs; slot lane*8 = X[group*16 + (lane&15)][k32*32 + (lane>>4)*8 ..+8].
// A wave touching one chunk reads/writes base + lane*16B: ONE 1KB transaction.

// ---------- kernel 1: merged conversion (A-gather + W-repack), one launch ----------
// Blocks 0..NBLK_A-1: gather+convert A (scatter reads hidden by 8-blocks/CU TLP
// -- round-3 lesson: this pattern must NOT live inside the lockstep GEMM).
// Blocks NBLK_A..: repack W via padded LDS tile.
__global__ __launch_bounds__(256) void conv_aw_kernel(
        const float* __restrict__ act, const float* __restrict__ W,
        f16* __restrict__ Afrag, f16* __restrict__ Bfrag) {
    __shared__ float tile[64][68];                 // [k][n], pad 68 (W path only)
    const int bid = blockIdx.x;
    const int t   = threadIdx.x;
    if (bid < NBLK_A) {
        const int chunkId = bid * 4 + (t >> 6);    // 65536 chunks
        const int lane = t & 63;
        const int q  = lane >> 4;
        const int rr = lane & 15;
        const int mg  = chunkId >> 8;              // m-16-group (KCHUNKS=256)
        const int k32 = chunkId & 255;
        const int k  = k32 * 32 + q * 8;           // 32-aligned chunk: one shard
        const int r  = k >> 10;
        const int kl = k & (KL_ - 1);
        const int m  = mg * 16 + rr;
        const float4* src = (const float4*)(act + ((size_t)r * M_DIM + m) * KL_ + kl);
        float4 a = src[0], b = src[1];
        *(f16x8*)(Afrag + (size_t)chunkId * 512 + lane * 8) = cvt8(a, b);
        return;
    }
    const int b2 = bid - NBLK_A;
    const int n0 = (b2 & 15) * 64;
    const int k0 = (b2 >> 4) * 64;
    #pragma unroll
    for (int l = 0; l < 4; l++) {
        int kr = l * 16 + (t >> 4);
        float4 v = *(const float4*)&W[(size_t)(k0 + kr) * N_DIM + n0 + (t & 15) * 4];
        *(float4*)&tile[kr][(t & 15) * 4] = v;
    }
    __syncthreads();
    const int jtl   = t >> 6;
    const int kt32l = (t >> 5) & 1;
    const int u     = t & 31;
    const int rr    = u & 15;
    const int qp    = u >> 4;
    f16x8 h0, h1;
    #pragma unroll
    for (int kk = 0; kk < 8; kk++)
        h0[kk] = (f16)tile[kt32l * 32 + qp * 16 + kk][jtl * 16 + rr];
    #pragma unroll
    for (int kk = 0; kk < 8; kk++)
        h1[kk] = (f16)tile[kt32l * 32 + qp * 16 + 8 + kk][jtl * 16 + rr];
    size_t chunk = (size_t)(n0 / 16 + jtl) * KCHUNKS + (k0 / 32 + kt32l);
    f16* dst = Bfrag + chunk * 512;
    *(f16x8*)(dst + ((2 * qp)     * 16 + rr) * 8) = h0;
    *(f16x8*)(dst + ((2 * qp + 1) * 16 + rr) * 8) = h1;
}

// ---------- kernel 2: 8-phase-style deep-pipelined fragment GEMM (r2-verified) ----------
// 256x256 tile, 8 waves (2M x 4N), BK=64 (2 k32), double-buffered 2x64KB LDS.
// Per K-tile: 4 phases x {ds_read subtile, stage 1 segment of tile t+1,
// barrier, setprio(1), 16 MFMA, setprio(0), [counted vmcnt], barrier}.
// vmcnt(4): consumed segment is always 2 segments (4 loads) older than the
// newest issue -> counted wait, never 0 in the main loop (T4).
// ONLY change vs round 2: partials stored as fp16 (quantization err <=~2e-3
// on sd~0.5 partials; negligible vs 0.03125 fp16-input floor).
__global__ __launch_bounds__(512, 2) void gemm_frag_kernel(
        const f16* __restrict__ Afrag,
        const f16* __restrict__ Bfrag,
        f16* __restrict__ part) {                 // (SPLITK, M, N) fp16
    __shared__ f16 sm[2][64 * 512];               // A chunks 0..31 (mg*2+k2), B 32..63

    const int tid  = threadIdx.x;
    const int w    = tid >> 6;                    // wave 0..7
    const int lane = tid & 63;
    const int q    = lane >> 4;
    const int rr   = lane & 15;
    const int wr   = w >> 2;                      // 0..1 (M)
    const int wc   = w & 3;                       // 0..3 (N)

    // XCD decode: xcd = (z<<1)|(mb&1). Per XCD: one z (B slice L2-resident),
    // 8 unique mb panels, all 4 nb (A panel reused x4 in L2).
    const int id   = blockIdx.x;                  // 0..255
    const int xcd  = id & 7;
    const int slot = id >> 3;                     // 0..31
    const int z    = xcd >> 1;                    // 0..3
    const int mb   = (slot >> 2) * 2 + (xcd & 1); // 0..15
    const int nb   = slot & 3;                    // 0..3
    const int row0 = mb * BM;
    const int col0 = nb * BN;
    const int kb32 = z * (KSLICE / 32);           // first k32 of this z-slice
    const int mg0  = row0 >> 4;
    const int ng0  = col0 >> 4;

    f32x4 acc[8][4];
    #pragma unroll
    for (int m = 0; m < 8; m++)
        #pragma unroll
        for (int n = 0; n < 4; n++)
            acc[m][n] = (f32x4){0.f, 0.f, 0.f, 0.f};

    f16x8 af[8];   // A fragments of current k2 half (reused across 2 n-phases)
    f16x8 bf[2];   // B fragments of current phase

#define STAGE_A(B_, T_, K2_) do { \
    const int kt32_ = kb32 + 2 * (T_) + (K2_); \
    _Pragma("unroll") \
    for (int j_ = 0; j_ < 2; j_++) { \
        const int mg_ = 2 * w + j_; \
        const f16* g_ = Afrag + ((size_t)(mg0 + mg_) * KCHUNKS + kt32_) * 512 + lane * 8; \
        lds_load16(g_, &sm[B_][(mg_ * 2 + (K2_)) * 512 + lane * 8]); \
    } \
} while (0)

#define STAGE_B(B_, T_, K2_) do { \
    const int kt32_ = kb32 + 2 * (T_) + (K2_); \
    _Pragma("unroll") \
    for (int j_ = 0; j_ < 2; j_++) { \
        const int ng_ = 2 * w + j_; \
        const f16* g_ = Bfrag + ((size_t)(ng0 + ng_) * KCHUNKS + kt32_) * 512 + lane * 8; \
        lds_load16(g_, &sm[B_][(32 + ng_ * 2 + (K2_)) * 512 + lane * 8]); \
    } \
} while (0)

#define READ_A(B_, K2_) do { \
    _Pragma("unroll") \
    for (int mi_ = 0; mi_ < 8; mi_++) \
        af[mi_] = *(const f16x8*)&sm[B_][((wr * 8 + mi_) * 2 + (K2_)) * 512 + lane * 8]; \
} while (0)

#define READ_B(B_, K2_, NH_) do { \
    _Pragma("unroll") \
    for (int ni_ = 0; ni_ < 2; ni_++) \
        bf[ni_] = *(const f16x8*)&sm[B_][(32 + (wc * 4 + (NH_) * 2 + ni_) * 2 + (K2_)) * 512 + lane * 8]; \
} while (0)

#define MFMA16(NH_) do { \
    __builtin_amdgcn_s_setprio(1); \
    _Pragma("unroll") \
    for (int mi_ = 0; mi_ < 8; mi_++) \
        _Pragma("unroll") \
        for (int ni_ = 0; ni_ < 2; ni_++) \
            acc[mi_][(NH_) * 2 + ni_] = __builtin_amdgcn_mfma_f32_16x16x32_f16( \
                af[mi_], bf[ni_], acc[mi_][(NH_) * 2 + ni_], 0, 0, 0); \
    __builtin_amdgcn_s_setprio(0); \
} while (0)

#define BAR() do { \
    asm volatile("" ::: "memory"); \
    __builtin_amdgcn_s_barrier(); \
    asm volatile("" ::: "memory"); \
} while (0)
#define SBAR0() __builtin_amdgcn_sched_barrier(0)
#define VM4() asm volatile("s_waitcnt vmcnt(4)" ::: "memory")
#define VM0() asm volatile("s_waitcnt vmcnt(0)" ::: "memory")

// One K-tile = 4 phases. VMMID_ guards A1/B1 of tile T_ before ph2 reads;
// VMEND_ guards A0/B0 of tile T_+1 before next tile's ph0 reads.
#define TILE(P_, T_, STG_, VMMID_, VMEND_) do { \
    READ_A(P_, 0); READ_B(P_, 0, 0); \
    if (STG_) STAGE_A((P_) ^ 1, (T_) + 1, 0); \
    BAR(); SBAR0(); MFMA16(0); BAR(); \
    READ_B(P_, 0, 1); \
    if (STG_) STAGE_B((P_) ^ 1, (T_) + 1, 0); \
    BAR(); SBAR0(); MFMA16(1); VMMID_; BAR(); \
    READ_A(P_, 1); READ_B(P_, 1, 0); \
    if (STG_) STAGE_A((P_) ^ 1, (T_) + 1, 1); \
    BAR(); SBAR0(); MFMA16(0); BAR(); \
    READ_B(P_, 1, 1); \
    if (STG_) STAGE_B((P_) ^ 1, (T_) + 1, 1); \
    BAR(); SBAR0(); MFMA16(1); VMEND_; BAR(); \
} while (0)

    // ---- prologue: stage tile 0 into buf0; wait for its first half ----
    STAGE_A(0, 0, 0);
    STAGE_B(0, 0, 0);
    STAGE_A(0, 0, 1);
    STAGE_B(0, 0, 1);
    VM4();                   // A0,B0(0) landed (A1,B1(0) still in flight)
    BAR();

    // ---- main loop: tiles 0..30 stage tile t+1; tail tile 31 drains ----
    #pragma unroll 1
    for (int t = 0; t < 30; t += 2) {
        TILE(0, t,     1, VM4(), VM4());
        TILE(1, t + 1, 1, VM4(), VM4());
    }
    TILE(0, 30, 1, VM4(), VM4());
    TILE(1, 31, 0, VM0(), (void)0);   // tail: no staging; drain once mid-tile

    // ---- epilogue: C/D layout col = lane&15, row = q*4 + reg (validated) ----
    f16* Pz = part + (size_t)z * M_DIM * N_DIM;
    #pragma unroll
    for (int m = 0; m < 8; m++) {
        const int gm = row0 + wr * 128 + m * 16 + q * 4;
        #pragma unroll
        for (int n = 0; n < 4; n++) {
            const int gn = col0 + wc * 64 + n * 16 + rr;
            #pragma unroll
            for (int r2 = 0; r2 < 4; r2++)
                Pz[(size_t)(gm + r2) * N_DIM + gn] = (f16)acc[m][n][r2];
        }
    }
#undef STAGE_A
#undef STAGE_B
#undef READ_A
#undef READ_B
#undef MFMA16
#undef BAR
#undef SBAR0
#undef VM4
#undef VM0
#undef TILE
}

// ---------- kernel 3: reduce 4 fp16 partials + bias -> fp32 out ----------
__global__ __launch_bounds__(256) void reduce_kernel(
        const f16* __restrict__ part, const float* __restrict__ bias,
        float* __restrict__ out) {
    int p = blockIdx.x * 256 + threadIdx.x;
    const f16x4* P = (const f16x4*)part;
    f16x4 s0 = P[p];
    f16x4 s1 = P[p + MN4];
    f16x4 s2 = P[p + 2 * MN4];
    f16x4 s3 = P[p + 3 * MN4];
    float4 b  = ((const float4*)bias)[p & (N_DIM / 4 - 1)];
    float4 r;
    r.x = (float)s0[0] + (float)s1[0] + (float)s2[0] + (float)s3[0] + b.x;
    r.y = (float)s0[1] + (float)s1[1] + (float)s2[1] + (float)s3[1] + b.y;
    r.z = (float)s0[2] + (float)s1[2] + (float)s2[2] + (float)s3[2] + b.z;
    r.w = (float)s0[3] + (float)s1[3] + (float)s2[3] + (float)s3[3] + b.w;
    ((float4*)out)[p] = r;
}

// ---------- fallback (only if ws too small): naive fp32 tiled GEMM ----------
__global__ void gemm_fallback_kernel(const float* __restrict__ act,
                                     const float* __restrict__ W,
                                     const float* __restrict__ bias,
                                     float* __restrict__ out) {
    __shared__ float sA2[32][33];
    __shared__ float sB2[32][33];
    int tx = threadIdx.x, ty = threadIdx.y;
    int m = blockIdx.y * 32 + ty;
    int n = blockIdx.x * 32 + tx;
    float acc = 0.f;
    for (int kt = 0; kt < K_DIM; kt += 32) {
        int ka = kt + tx;
        int r = ka >> 10, kl = ka & (KL_ - 1);
        sA2[ty][tx] = act[((size_t)r * M_DIM + m) * KL_ + kl];
        sB2[ty][tx] = W[(size_t)(kt + ty) * N_DIM + n];
        __syncthreads();
        #pragma unroll
        for (int kk = 0; kk < 32; kk++) acc += sA2[ty][kk] * sB2[kk][tx];
        __syncthreads();
    }
    out[(size_t)m * N_DIM + n] = acc + bias[n];
}

extern "C" void kernel_launch(void* const* d_in, const int* in_sizes, int n_in,
                              void* d_out, int out_size, void* d_ws, size_t ws_size,
                              hipStream_t stream) {
    const float* all_act = (const float*)d_in[0];
    const float* local_W = (const float*)d_in[1];
    const float* bias    = (const float*)d_in[2];
    float* out = (float*)d_out;

    const size_t partBytes = (size_t)SPLITK * M_DIM * N_DIM * sizeof(f16);    // 33.6 MB
    const size_t elemsA    = (size_t)M_DIM * K_DIM;                           // 33.5M
    const size_t elemsW    = (size_t)K_DIM * N_DIM;                           // 8.4M
    const size_t need = partBytes + elemsA * sizeof(f16) + elemsW * sizeof(f16);  // ~117 MB

    if (ws_size < need) {
        gemm_fallback_kernel<<<dim3(N_DIM / 32, M_DIM / 32), dim3(32, 32), 0, stream>>>(
            all_act, local_W, bias, out);
        return;
    }

    f16* part  = (f16*)d_ws;
    f16* Afrag = (f16*)((char*)d_ws + partBytes);
    f16* Bfrag = Afrag + elemsA;

    conv_aw_kernel<<<NBLK_A + NBLK_W, 256, 0, stream>>>(all_act, local_W, Afrag, Bfrag);
    gemm_frag_kernel<<<256, 512, 0, stream>>>(Afrag, Bfrag, part);
    reduce_kernel<<<MN4 / 256, 256, 0, stream>>>(part, bias, out);
}

// Round 5
// 293.929 us; speedup vs baseline: 1.0490x; 1.0027x over previous
//
#include <hip/hip_runtime.h>
#include <stdint.h>

// Problem constants (fixed by reference)
#define TP_      8
#define M_DIM    4096
#define K_DIM    8192
#define N_DIM    1024      // N_LOCAL
#define KL_      1024      // K_LOCAL
#define BM       256
#define BN       256
#define SPLITK   4
#define KSLICE   (K_DIM / SPLITK)   // 2048
#define MN4      (M_DIM * N_DIM / 4)
#define KCHUNKS  (K_DIM / 32)       // 256 k32-chunks per 16-row/col group
#define AK       512                // k-floats per A-conversion tile
#define NBLK_A   ((M_DIM / 16) * (K_DIM / AK))     // 256*16 = 4096 conv-A blocks
#define NBLK_W   ((N_DIM / 64) * (K_DIM / 64))     // 2048 conv-W blocks

typedef _Float16 f16;
typedef f16 f16x8 __attribute__((ext_vector_type(8)));
typedef f16 f16x4 __attribute__((ext_vector_type(4)));
typedef float f32x4 __attribute__((ext_vector_type(4)));

// 8x fp32 -> fp16 (v_cvt_f16_f32, RN)
__device__ __forceinline__ f16x8 cvt8(float4 a, float4 b) {
    f16x8 r;
    r[0] = (f16)a.x; r[1] = (f16)a.y; r[2] = (f16)a.z; r[3] = (f16)a.w;
    r[4] = (f16)b.x; r[5] = (f16)b.y; r[6] = (f16)b.z; r[7] = (f16)b.w;
    return r;
}

// async global->LDS, 16B/lane; dest = wave-uniform base + lane*16 (m104/m108)
__device__ __forceinline__ void lds_load16(const void* g, void* l) {
    __builtin_amdgcn_global_load_lds(
        (const __attribute__((address_space(1))) void*)g,
        (__attribute__((address_space(3))) void*)l, 16, 0, 0);
}

// Fragment-major layout (both operands): chunk c = group*KCHUNKS + k32;
// chunk holds 512 halfs; slot lane*8 = X[group*16 + (lane&15)][k32*32 + (lane>>4)*8 ..+8].
// A wave touching one chunk reads/writes base + lane*16B: ONE 1KB transaction.

// ---------- kernel 1: merged conversion (A-gather + W-repack), one launch ----------
// Round-5 fix: A path reads were 16 scattered 64B half-lines per inst (2.06
// TB/s measured, r4). Now LDS-bounced like the W path: phase 1 = coalesced
// reads (per inst: 4 rows x 256B contiguous segments), phase 2 = frag-pattern
// LDS reads (2-way max, free) + wave-uniform 1KB frag-major writes.
__global__ __launch_bounds__(256) void conv_aw_kernel(
        const float* __restrict__ act, const float* __restrict__ W,
        f16* __restrict__ Afrag, f16* __restrict__ Bfrag) {
    __shared__ __align__(16) char shraw[16 * (AK + 4) * sizeof(float)];  // 33KB
    const int bid = blockIdx.x;
    const int t   = threadIdx.x;

    if (bid < NBLK_A) {
        float (*ta)[AK + 4] = (float(*)[AK + 4])shraw;
        const int mg = bid >> 4;               // m-16-group 0..255
        const int kt = bid & 15;               // k-tile of 512 floats
        const int k0 = kt * AK;                // 512 | 1024 -> single shard
        const int r  = k0 >> 10;
        const int kl = k0 & (KL_ - 1);
        const int row  = t >> 4;               // 0..15
        const int cseg = t & 15;
        // phase 1: coalesced global -> LDS. inst i: lanes 0-15 = row0's
        // bytes [i*256, i*256+256) contiguous; 4 rows per wave-inst.
        const float* src = act + ((size_t)r * M_DIM + mg * 16 + row) * KL_ + kl + cseg * 4;
        #pragma unroll
        for (int i = 0; i < 8; i++) {
            float4 v = *(const float4*)(src + i * 64);
            *(float4*)&ta[row][cseg * 4 + i * 64] = v;
        }
        __syncthreads();
        // phase 2: frag-pattern LDS read + coalesced frag-major write.
        const int l  = t & 63;
        const int wv = t >> 6;
        const int rr = l & 15;
        const int q  = l >> 4;
        #pragma unroll
        for (int j = 0; j < 4; j++) {
            const int c = wv + j * 4;          // chunk within tile (wave-uniform)
            float4 x = *(const float4*)&ta[rr][c * 32 + q * 8];
            float4 y = *(const float4*)&ta[rr][c * 32 + q * 8 + 4];
            size_t chunk = (size_t)mg * KCHUNKS + kt * 16 + c;
            *(f16x8*)(Afrag + chunk * 512 + l * 8) = cvt8(x, y);  // 1KB/wave
        }
        return;
    }

    float (*tile)[68] = (float(*)[68])shraw;   // [k][n], pad 68 (W path)
    const int b2 = bid - NBLK_A;
    const int n0 = (b2 & 15) * 64;
    const int k0 = (b2 >> 4) * 64;
    #pragma unroll
    for (int l = 0; l < 4; l++) {
        int kr = l * 16 + (t >> 4);
        float4 v = *(const float4*)&W[(size_t)(k0 + kr) * N_DIM + n0 + (t & 15) * 4];
        *(float4*)&tile[kr][(t & 15) * 4] = v;
    }
    __syncthreads();
    const int jtl   = t >> 6;
    const int kt32l = (t >> 5) & 1;
    const int u     = t & 31;
    const int rr    = u & 15;
    const int qp    = u >> 4;
    f16x8 h0, h1;
    #pragma unroll
    for (int kk = 0; kk < 8; kk++)
        h0[kk] = (f16)tile[kt32l * 32 + qp * 16 + kk][jtl * 16 + rr];
    #pragma unroll
    for (int kk = 0; kk < 8; kk++)
        h1[kk] = (f16)tile[kt32l * 32 + qp * 16 + 8 + kk][jtl * 16 + rr];
    size_t chunk = (size_t)(n0 / 16 + jtl) * KCHUNKS + (k0 / 32 + kt32l);
    f16* dst = Bfrag + chunk * 512;
    *(f16x8*)(dst + ((2 * qp)     * 16 + rr) * 8) = h0;
    *(f16x8*)(dst + ((2 * qp + 1) * 16 + rr) * 8) = h1;
}

// ---------- kernel 2: 8-phase-style deep-pipelined fragment GEMM (r2/r4-verified) ----------
// 256x256 tile, 8 waves (2M x 4N), BK=64 (2 k32), double-buffered 2x64KB LDS.
// Per K-tile: 4 phases x {ds_read subtile, stage 1 segment of tile t+1,
// barrier, setprio(1), 16 MFMA, setprio(0), [counted vmcnt], barrier}.
// vmcnt(4): consumed segment is always 2 segments (4 loads) older than the
// newest issue -> counted wait, never 0 in the main loop (T4).
// Partials stored fp16 (r4-verified: absmax floor unchanged).
__global__ __launch_bounds__(512, 2) void gemm_frag_kernel(
        const f16* __restrict__ Afrag,
        const f16* __restrict__ Bfrag,
        f16* __restrict__ part) {                 // (SPLITK, M, N) fp16
    __shared__ f16 sm[2][64 * 512];               // A chunks 0..31 (mg*2+k2), B 32..63

    const int tid  = threadIdx.x;
    const int w    = tid >> 6;                    // wave 0..7
    const int lane = tid & 63;
    const int q    = lane >> 4;
    const int rr   = lane & 15;
    const int wr   = w >> 2;                      // 0..1 (M)
    const int wc   = w & 3;                       // 0..3 (N)

    // XCD decode: xcd = (z<<1)|(mb&1). Per XCD: one z (B slice L2-resident),
    // 8 unique mb panels, all 4 nb (A panel reused x4 in L2).
    const int id   = blockIdx.x;                  // 0..255
    const int xcd  = id & 7;
    const int slot = id >> 3;                     // 0..31
    const int z    = xcd >> 1;                    // 0..3
    const int mb   = (slot >> 2) * 2 + (xcd & 1); // 0..15
    const int nb   = slot & 3;                    // 0..3
    const int row0 = mb * BM;
    const int col0 = nb * BN;
    const int kb32 = z * (KSLICE / 32);           // first k32 of this z-slice
    const int mg0  = row0 >> 4;
    const int ng0  = col0 >> 4;

    f32x4 acc[8][4];
    #pragma unroll
    for (int m = 0; m < 8; m++)
        #pragma unroll
        for (int n = 0; n < 4; n++)
            acc[m][n] = (f32x4){0.f, 0.f, 0.f, 0.f};

    f16x8 af[8];   // A fragments of current k2 half (reused across 2 n-phases)
    f16x8 bf[2];   // B fragments of current phase

#define STAGE_A(B_, T_, K2_) do { \
    const int kt32_ = kb32 + 2 * (T_) + (K2_); \
    _Pragma("unroll") \
    for (int j_ = 0; j_ < 2; j_++) { \
        const int mg_ = 2 * w + j_; \
        const f16* g_ = Afrag + ((size_t)(mg0 + mg_) * KCHUNKS + kt32_) * 512 + lane * 8; \
        lds_load16(g_, &sm[B_][(mg_ * 2 + (K2_)) * 512 + lane * 8]); \
    } \
} while (0)

#define STAGE_B(B_, T_, K2_) do { \
    const int kt32_ = kb32 + 2 * (T_) + (K2_); \
    _Pragma("unroll") \
    for (int j_ = 0; j_ < 2; j_++) { \
        const int ng_ = 2 * w + j_; \
        const f16* g_ = Bfrag + ((size_t)(ng0 + ng_) * KCHUNKS + kt32_) * 512 + lane * 8; \
        lds_load16(g_, &sm[B_][(32 + ng_ * 2 + (K2_)) * 512 + lane * 8]); \
    } \
} while (0)

#define READ_A(B_, K2_) do { \
    _Pragma("unroll") \
    for (int mi_ = 0; mi_ < 8; mi_++) \
        af[mi_] = *(const f16x8*)&sm[B_][((wr * 8 + mi_) * 2 + (K2_)) * 512 + lane * 8]; \
} while (0)

#define READ_B(B_, K2_, NH_) do { \
    _Pragma("unroll") \
    for (int ni_ = 0; ni_ < 2; ni_++) \
        bf[ni_] = *(const f16x8*)&sm[B_][(32 + (wc * 4 + (NH_) * 2 + ni_) * 2 + (K2_)) * 512 + lane * 8]; \
} while (0)

#define MFMA16(NH_) do { \
    __builtin_amdgcn_s_setprio(1); \
    _Pragma("unroll") \
    for (int mi_ = 0; mi_ < 8; mi_++) \
        _Pragma("unroll") \
        for (int ni_ = 0; ni_ < 2; ni_++) \
            acc[mi_][(NH_) * 2 + ni_] = __builtin_amdgcn_mfma_f32_16x16x32_f16( \
                af[mi_], bf[ni_], acc[mi_][(NH_) * 2 + ni_], 0, 0, 0); \
    __builtin_amdgcn_s_setprio(0); \
} while (0)

#define BAR() do { \
    asm volatile("" ::: "memory"); \
    __builtin_amdgcn_s_barrier(); \
    asm volatile("" ::: "memory"); \
} while (0)
#define SBAR0() __builtin_amdgcn_sched_barrier(0)
#define VM4() asm volatile("s_waitcnt vmcnt(4)" ::: "memory")
#define VM0() asm volatile("s_waitcnt vmcnt(0)" ::: "memory")

// One K-tile = 4 phases. VMMID_ guards A1/B1 of tile T_ before ph2 reads;
// VMEND_ guards A0/B0 of tile T_+1 before next tile's ph0 reads.
#define TILE(P_, T_, STG_, VMMID_, VMEND_) do { \
    READ_A(P_, 0); READ_B(P_, 0, 0); \
    if (STG_) STAGE_A((P_) ^ 1, (T_) + 1, 0); \
    BAR(); SBAR0(); MFMA16(0); BAR(); \
    READ_B(P_, 0, 1); \
    if (STG_) STAGE_B((P_) ^ 1, (T_) + 1, 0); \
    BAR(); SBAR0(); MFMA16(1); VMMID_; BAR(); \
    READ_A(P_, 1); READ_B(P_, 1, 0); \
    if (STG_) STAGE_A((P_) ^ 1, (T_) + 1, 1); \
    BAR(); SBAR0(); MFMA16(0); BAR(); \
    READ_B(P_, 1, 1); \
    if (STG_) STAGE_B((P_) ^ 1, (T_) + 1, 1); \
    BAR(); SBAR0(); MFMA16(1); VMEND_; BAR(); \
} while (0)

    // ---- prologue: stage tile 0 into buf0; wait for its first half ----
    STAGE_A(0, 0, 0);
    STAGE_B(0, 0, 0);
    STAGE_A(0, 0, 1);
    STAGE_B(0, 0, 1);
    VM4();                   // A0,B0(0) landed (A1,B1(0) still in flight)
    BAR();

    // ---- main loop: tiles 0..30 stage tile t+1; tail tile 31 drains ----
    #pragma unroll 1
    for (int t = 0; t < 30; t += 2) {
        TILE(0, t,     1, VM4(), VM4());
        TILE(1, t + 1, 1, VM4(), VM4());
    }
    TILE(0, 30, 1, VM4(), VM4());
    TILE(1, 31, 0, VM0(), (void)0);   // tail: no staging; drain once mid-tile

    // ---- epilogue: C/D layout col = lane&15, row = q*4 + reg (validated) ----
    f16* Pz = part + (size_t)z * M_DIM * N_DIM;
    #pragma unroll
    for (int m = 0; m < 8; m++) {
        const int gm = row0 + wr * 128 + m * 16 + q * 4;
        #pragma unroll
        for (int n = 0; n < 4; n++) {
            const int gn = col0 + wc * 64 + n * 16 + rr;
            #pragma unroll
            for (int r2 = 0; r2 < 4; r2++)
                Pz[(size_t)(gm + r2) * N_DIM + gn] = (f16)acc[m][n][r2];
        }
    }
#undef STAGE_A
#undef STAGE_B
#undef READ_A
#undef READ_B
#undef MFMA16
#undef BAR
#undef SBAR0
#undef VM4
#undef VM0
#undef TILE
}

// ---------- kernel 3: reduce 4 fp16 partials + bias -> fp32 out ----------
__global__ __launch_bounds__(256) void reduce_kernel(
        const f16* __restrict__ part, const float* __restrict__ bias,
        float* __restrict__ out) {
    int p = blockIdx.x * 256 + threadIdx.x;
    const f16x4* P = (const f16x4*)part;
    f16x4 s0 = P[p];
    f16x4 s1 = P[p + MN4];
    f16x4 s2 = P[p + 2 * MN4];
    f16x4 s3 = P[p + 3 * MN4];
    float4 b  = ((const float4*)bias)[p & (N_DIM / 4 - 1)];
    float4 r;
    r.x = (float)s0[0] + (float)s1[0] + (float)s2[0] + (float)s3[0] + b.x;
    r.y = (float)s0[1] + (float)s1[1] + (float)s2[1] + (float)s3[1] + b.y;
    r.z = (float)s0[2] + (float)s1[2] + (float)s2[2] + (float)s3[2] + b.z;
    r.w = (float)s0[3] + (float)s1[3] + (float)s2[3] + (float)s3[3] + b.w;
    ((float4*)out)[p] = r;
}

// ---------- fallback (only if ws too small): naive fp32 tiled GEMM ----------
__global__ void gemm_fallback_kernel(const float* __restrict__ act,
                                     const float* __restrict__ W,
                                     const float* __restrict__ bias,
                                     float* __restrict__ out) {
    __shared__ float sA2[32][33];
    __shared__ float sB2[32][33];
    int tx = threadIdx.x, ty = threadIdx.y;
    int m = blockIdx.y * 32 + ty;
    int n = blockIdx.x * 32 + tx;
    float acc = 0.f;
    for (int kt = 0; kt < K_DIM; kt += 32) {
        int ka = kt + tx;
        int r = ka >> 10, kl = ka & (KL_ - 1);
        sA2[ty][tx] = act[((size_t)r * M_DIM + m) * KL_ + kl];
        sB2[ty][tx] = W[(size_t)(kt + ty) * N_DIM + n];
        __syncthreads();
        #pragma unroll
        for (int kk = 0; kk < 32; kk++) acc += sA2[ty][kk] * sB2[kk][tx];
        __syncthreads();
    }
    out[(size_t)m * N_DIM + n] = acc + bias[n];
}

extern "C" void kernel_launch(void* const* d_in, const int* in_sizes, int n_in,
                              void* d_out, int out_size, void* d_ws, size_t ws_size,
                              hipStream_t stream) {
    const float* all_act = (const float*)d_in[0];
    const float* local_W = (const float*)d_in[1];
    const float* bias    = (const float*)d_in[2];
    float* out = (float*)d_out;

    const size_t partBytes = (size_t)SPLITK * M_DIM * N_DIM * sizeof(f16);    // 33.6 MB
    const size_t elemsA    = (size_t)M_DIM * K_DIM;                           // 33.5M
    const size_t elemsW    = (size_t)K_DIM * N_DIM;                           // 8.4M
    const size_t need = partBytes + elemsA * sizeof(f16) + elemsW * sizeof(f16);  // ~117 MB

    if (ws_size < need) {
        gemm_fallback_kernel<<<dim3(N_DIM / 32, M_DIM / 32), dim3(32, 32), 0, stream>>>(
            all_act, local_W, bias, out);
        return;
    }

    f16* part  = (f16*)d_ws;
    f16* Afrag = (f16*)((char*)d_ws + partBytes);
    f16* Bfrag = Afrag + elemsA;

    conv_aw_kernel<<<NBLK_A + NBLK_W, 256, 0, stream>>>(all_act, local_W, Afrag, Bfrag);
    gemm_frag_kernel<<<256, 512, 0, stream>>>(Afrag, Bfrag, part);
    reduce_kernel<<<MN4 / 256, 256, 0, stream>>>(part, bias, out);
}